// Round 1
// baseline (140.755 us; speedup 1.0000x reference)
//
#include <hip/hip_runtime.h>

// Involution2d: B=8, C=256, G=4 (Cpg=64), H=W=Ho=Wo=64, K=7, PAD=3, STRIDE=1.
// out[b, g*64+c, y, x] = sum_{kh,kw} in[b, g*64+c, y+kh-3, x+kw-3] * w[b,g,kh,kw,y,x] + bias[g*64+c]
//
// Occupancy-first restructure vs previous version:
//  - Weights are STREAMED (7 float4 live per kh, 28 VGPR), accumulators are
//    RESIDENT (acc[NC=4][4] = 16 VGPR). Previous kernel held 49 float4 =
//    196 floats of weights -> compiler spilled (VGPR_Count=128 < 196+).
//  - All NC=4 channels staged in LDS ONCE -> exactly one __syncthreads per
//    block (previous: ~31 barriers from per-channel restaging).
//  - 256-thread blocks, grid (4,16,32)=2048 blocks * 4 waves = 8192 waves
//    (previous: 2048 waves -> 2/SIMD grid-limited, 17% occupancy).
//  - LDS: per-channel row-major, stride 72 floats (16B-aligned rows) ->
//    ds_read_b128 reads; (idx/4)%8 = (4c+2row+tx)%8 spreads lanes uniformly
//    over b128 phases -> bank-conflict-free without swizzle.

#define BLK_X 16
#define BLK_Y 16
#define NTHR  256
#define NC    4              // channels per block
#define ROWS  16             // output rows per block
#define S_ROWS 22            // ROWS + 6 halo
#define S_STRIDE 72          // 64 + 6 halo, padded to 72 (16B-aligned rows)
#define S_CH (S_ROWS * S_STRIDE)   // 1584 floats per channel
#define S_ELEMS (S_ROWS * 70)      // 1540 staged elements per channel

__global__ __launch_bounds__(NTHR, 4)
void involution_kernel(const float* __restrict__ in,
                       const float* __restrict__ w,
                       const float* __restrict__ bias,
                       float* __restrict__ out) {
    __shared__ float lds[NC * S_CH];   // 25,344 B -> up to 6 blocks/CU by LDS

    const int tx  = threadIdx.x;       // 0..15  (x-quad)
    const int ty  = threadIdx.y;       // 0..15  (row)
    const int tid = ty * BLK_X + tx;   // 0..255
    const int x0  = tx * 4;
    const int Y0  = blockIdx.x * ROWS;
    const int y   = Y0 + ty;
    const int c0  = blockIdx.y * NC;   // channel-in-group base
    const int bz  = blockIdx.z;        // b*4 + g
    const int g   = bz & 3;

    const float* inb  = in  + (size_t)bz * 64 * 4096;
    float*       outb = out + (size_t)bz * 64 * 4096;
    const float* wb   = w   + (size_t)bz * 49 * 4096 + y * 64 + x0;

    // ---- stage NC channels (once; single barrier) ----
    #pragma unroll
    for (int c = 0; c < NC; ++c) {
        const float* p = inb + (size_t)(c0 + c) * 4096;
        float* l = lds + c * S_CH;
        #pragma unroll
        for (int j = 0; j < 7; ++j) {
            int i = tid + j * NTHR;          // 0..1791
            if (i < S_ELEMS) {
                int r  = i / 70;             // staged row 0..21
                int cl = i - r * 70;         // staged col 0..69
                int gy = Y0 + r - 3;
                int gx = cl - 3;
                float v = 0.f;
                if (gy >= 0 && gy < 64 && gx >= 0 && gx < 64)
                    v = p[gy * 64 + gx];
                l[r * S_STRIDE + cl] = v;
            }
        }
    }
    __syncthreads();

    float acc[NC][4];
    #pragma unroll
    for (int c = 0; c < NC; ++c) {
        acc[c][0] = 0.f; acc[c][1] = 0.f; acc[c][2] = 0.f; acc[c][3] = 0.f;
    }

    // ---- kh-outer: only 7 weight float4 live at a time ----
    #pragma unroll 1
    for (int kh = 0; kh < 7; ++kh) {
        float4 wv[7];
        #pragma unroll
        for (int kw = 0; kw < 7; ++kw)
            wv[kw] = *(const float4*)(wb + (size_t)(kh * 7 + kw) * 4096);

        #pragma unroll
        for (int c = 0; c < NC; ++c) {
            const float* lr = lds + c * S_CH + (ty + kh) * S_STRIDE + x0;
            // 16B-aligned: offset = c*1584 + row*72 + 4*tx (all mult. of 4 floats)
            float4 va = *(const float4*)(lr);
            float4 vb = *(const float4*)(lr + 4);
            float2 vc = *(const float2*)(lr + 8);
            float vals[10] = {va.x, va.y, va.z, va.w,
                              vb.x, vb.y, vb.z, vb.w,
                              vc.x, vc.y};
            #pragma unroll
            for (int kw = 0; kw < 7; ++kw) {
                acc[c][0] += vals[kw + 0] * wv[kw].x;
                acc[c][1] += vals[kw + 1] * wv[kw].y;
                acc[c][2] += vals[kw + 2] * wv[kw].z;
                acc[c][3] += vals[kw + 3] * wv[kw].w;
            }
        }
    }

    // ---- epilogue ----
    #pragma unroll
    for (int c = 0; c < NC; ++c) {
        const float bv = bias[g * 64 + c0 + c];
        float4 o;
        o.x = acc[c][0] + bv;
        o.y = acc[c][1] + bv;
        o.z = acc[c][2] + bv;
        o.w = acc[c][3] + bv;
        *(float4*)(outb + (size_t)(c0 + c) * 4096 + y * 64 + x0) = o;
    }
}

extern "C" void kernel_launch(void* const* d_in, const int* in_sizes, int n_in,
                              void* d_out, int out_size, void* d_ws, size_t ws_size,
                              hipStream_t stream) {
    const float* in   = (const float*)d_in[0];  // (8,256,64,64)
    const float* wgt  = (const float*)d_in[1];  // (8,4,7,7,64,64)
    const float* bias = (const float*)d_in[2];  // (256,)
    float* out = (float*)d_out;                 // (8,256,64,64)

    dim3 block(BLK_X, BLK_Y, 1);                   // 256 threads = 4 waves
    dim3 grid(64 / ROWS, 64 / NC, 32);             // (4, 16, 32) = 2048 blocks
    involution_kernel<<<grid, block, 0, stream>>>(in, wgt, bias, out);
}

// Round 2
// 138.232 us; speedup vs baseline: 1.0182x; 1.0182x over previous
//
#include <hip/hip_runtime.h>

// Involution2d: B=8, C=256, G=4 (Cpg=64), H=W=Ho=Wo=64, K=7, PAD=3, STRIDE=1.
// out[b, g*64+c, y, x] = sum_{kh,kw} in[b, g*64+c, y+kh-3, x+kw-3] * w[b,g,kh,kw,y,x] + bias[g*64+c]
//
// Round-2 theory: round-1's VGPR_Count=40 proved the compiler's occupancy
// heuristic register-squeezed the body, sinking weight loads into the channel
// loop (serial L2-latency stalls -> VALUBusy 23%). This version:
//  - amdgpu_waves_per_eu(4,4): pins the budget at 128 VGPR, stops the squeeze.
//  - Explicit kh double-buffer (wA/wB, static names, fully unrolled): weight
//    loads for kh+1 issue a full compute phase (~450 cyc) before use.
//  - Explicit channel ping-pong (vp/vn): ds_reads for c+1 in flight while
//    computing c.
//  - kh=0 weights issued before staging, kh=1 before the barrier.
// Geometry unchanged vs round 1 (it was fine): 256 thr, NC=4 ch/block,
// 16 rows/block, one barrier, LDS 25.3 KB.

#define BLK_X 16
#define BLK_Y 16
#define NTHR  256
#define NC    4
#define ROWS  16
#define S_ROWS 22            // ROWS + 6 halo
#define S_STRIDE 72          // 70 cols padded to 72 (16B-aligned rows)
#define S_CH (S_ROWS * S_STRIDE)
#define S_ELEMS (S_ROWS * 70)

// read 12 staged floats (3x ds_read_b128) for channel C, kernel row KH
#define LOAD_VALS(dst, C, KH) do {                                         \
    const float* lr_ = lds + (C) * S_CH + (ty + (KH)) * S_STRIDE + x0;     \
    float4 t0_ = *(const float4*)(lr_);                                    \
    float4 t1_ = *(const float4*)(lr_ + 4);                                \
    float4 t2_ = *(const float4*)(lr_ + 8);                                \
    dst[0]=t0_.x; dst[1]=t0_.y; dst[2]=t0_.z;  dst[3]=t0_.w;               \
    dst[4]=t1_.x; dst[5]=t1_.y; dst[6]=t1_.z;  dst[7]=t1_.w;               \
    dst[8]=t2_.x; dst[9]=t2_.y; dst[10]=t2_.z; dst[11]=t2_.w;              \
} while (0)

#define FMA_C(C, V, W) do {                                                \
    _Pragma("unroll")                                                      \
    for (int kw_ = 0; kw_ < 7; ++kw_) {                                    \
        acc[C][0] += V[kw_ + 0] * W[kw_].x;                                \
        acc[C][1] += V[kw_ + 1] * W[kw_].y;                                \
        acc[C][2] += V[kw_ + 2] * W[kw_].z;                                \
        acc[C][3] += V[kw_ + 3] * W[kw_].w;                                \
    }                                                                      \
} while (0)

// one kh row: ping-pong vals across the 4 channels (reads lead compute by 1)
#define COMP_KH(KH, W) do {                                                \
    float vp[12], vn[12];                                                  \
    LOAD_VALS(vp, 0, KH);                                                  \
    LOAD_VALS(vn, 1, KH);                                                  \
    FMA_C(0, vp, W);                                                       \
    LOAD_VALS(vp, 2, KH);                                                  \
    FMA_C(1, vn, W);                                                       \
    LOAD_VALS(vn, 3, KH);                                                  \
    FMA_C(2, vp, W);                                                       \
    FMA_C(3, vn, W);                                                       \
} while (0)

#define LOAD_W(dst, KH) do {                                               \
    _Pragma("unroll")                                                      \
    for (int kw_ = 0; kw_ < 7; ++kw_)                                      \
        dst[kw_] = *(const float4*)(wb + (size_t)((KH) * 7 + kw_) * 4096); \
} while (0)

__global__ __launch_bounds__(NTHR)
__attribute__((amdgpu_waves_per_eu(4, 4)))
void involution_kernel(const float* __restrict__ in,
                       const float* __restrict__ w,
                       const float* __restrict__ bias,
                       float* __restrict__ out) {
    __shared__ float lds[NC * S_CH];   // 25,344 B

    const int tx  = threadIdx.x;       // 0..15 (x-quad)
    const int ty  = threadIdx.y;       // 0..15 (row)
    const int tid = ty * BLK_X + tx;
    const int x0  = tx * 4;
    const int Y0  = blockIdx.x * ROWS;
    const int y   = Y0 + ty;
    const int c0  = blockIdx.y * NC;
    const int bz  = blockIdx.z;        // b*4 + g
    const int g   = bz & 3;

    const float* inb  = in  + (size_t)bz * 64 * 4096;
    float*       outb = out + (size_t)bz * 64 * 4096;
    const float* wb   = w   + (size_t)bz * 49 * 4096 + y * 64 + x0;

    // kh=0 weights first: longest latency, hides under staging
    float4 wA[7], wB[7];
    LOAD_W(wA, 0);

    // ---- stage NC channels (once; single barrier) ----
    #pragma unroll
    for (int c = 0; c < NC; ++c) {
        const float* p = inb + (size_t)(c0 + c) * 4096;
        float* l = lds + c * S_CH;
        #pragma unroll
        for (int j = 0; j < 7; ++j) {
            int i = tid + j * NTHR;          // 0..1791
            if (i < S_ELEMS) {
                int r  = i / 70;             // staged row 0..21
                int cl = i - r * 70;         // staged col 0..69
                int gy = Y0 + r - 3;
                int gx = cl - 3;
                float v = 0.f;
                if (gy >= 0 && gy < 64 && gx >= 0 && gx < 64)
                    v = p[gy * 64 + gx];
                l[r * S_STRIDE + cl] = v;
            }
        }
    }

    LOAD_W(wB, 1);         // kh=1 weights hide under the barrier
    __syncthreads();

    float acc[NC][4];
    #pragma unroll
    for (int c = 0; c < NC; ++c) {
        acc[c][0] = 0.f; acc[c][1] = 0.f; acc[c][2] = 0.f; acc[c][3] = 0.f;
    }

    // software-pipelined kh: compute(cur) while next buffer loads
    COMP_KH(0, wA);  LOAD_W(wA, 2);
    COMP_KH(1, wB);  LOAD_W(wB, 3);
    COMP_KH(2, wA);  LOAD_W(wA, 4);
    COMP_KH(3, wB);  LOAD_W(wB, 5);
    COMP_KH(4, wA);  LOAD_W(wA, 6);
    COMP_KH(5, wB);
    COMP_KH(6, wA);

    // ---- epilogue ----
    #pragma unroll
    for (int c = 0; c < NC; ++c) {
        const float bv = bias[g * 64 + c0 + c];
        float4 o;
        o.x = acc[c][0] + bv;
        o.y = acc[c][1] + bv;
        o.z = acc[c][2] + bv;
        o.w = acc[c][3] + bv;
        *(float4*)(outb + (size_t)(c0 + c) * 4096 + y * 64 + x0) = o;
    }
}

extern "C" void kernel_launch(void* const* d_in, const int* in_sizes, int n_in,
                              void* d_out, int out_size, void* d_ws, size_t ws_size,
                              hipStream_t stream) {
    const float* in   = (const float*)d_in[0];  // (8,256,64,64)
    const float* wgt  = (const float*)d_in[1];  // (8,4,7,7,64,64)
    const float* bias = (const float*)d_in[2];  // (256,)
    float* out = (float*)d_out;                 // (8,256,64,64)

    dim3 block(BLK_X, BLK_Y, 1);                   // 256 threads = 4 waves
    dim3 grid(64 / ROWS, 64 / NC, 32);             // (4, 16, 32) = 2048 blocks
    involution_kernel<<<grid, block, 0, stream>>>(in, wgt, bias, out);
}